// Round 2
// baseline (1198.400 us; speedup 1.0000x reference)
//
#include <hip/hip_runtime.h>
#include <cmath>

typedef unsigned short u16;
typedef unsigned int   u32;
typedef __attribute__((ext_vector_type(8))) short bf16x8;
typedef __attribute__((ext_vector_type(4))) float f32x4;
typedef __attribute__((ext_vector_type(4))) u32   u32x4;

__device__ __forceinline__ float bf2f(u16 u){
    union { u32 i; float f; } x; x.i = ((u32)u) << 16; return x.f;
}
__device__ __forceinline__ u16 f2bf(float f){
    union { float f; u32 i; } x; x.f = f;
    u32 r = x.i + 0x7fffu + ((x.i >> 16) & 1u);
    return (u16)(r >> 16);
}

// ---------------- graph preprocessing ----------------

__global__ void k_degrees(const int* __restrict__ src, const int* __restrict__ dst,
                          int* indeg, int* outdeg, int E){
    int e = blockIdx.x*256 + threadIdx.x;
    if (e < E){
        atomicAdd(&indeg[dst[e]], 1);
        atomicAdd(&outdeg[src[e]], 1);
    }
}

__global__ void k_degaux(const int* __restrict__ indeg, float* inv_deg, float* haspred, int N){
    int n = blockIdx.x*256 + threadIdx.x;
    if (n < N){
        int d = indeg[n];
        inv_deg[n] = 1.0f / (float)(d > 1 ? d : 1);
        haspred[n] = d > 0 ? 1.0f : 0.0f;
    }
}

__global__ void k_scan1(const int* __restrict__ in, int* blocksum, int N){
    __shared__ int sh[256];
    int tid = threadIdx.x;
    int base = blockIdx.x*1024 + tid*4;
    int s = 0;
    for (int j=0;j<4;j++){ int i = base+j; s += (i < N) ? in[i] : 0; }
    sh[tid] = s; __syncthreads();
    for (int d=128; d>0; d>>=1){ if (tid < d) sh[tid] += sh[tid+d]; __syncthreads(); }
    if (tid == 0) blocksum[blockIdx.x] = sh[0];
}

__global__ void k_scan2(int* blocksum, int nb){
    if (threadIdx.x == 0){
        int run = 0;
        for (int i=0;i<nb;i++){ int v = blocksum[i]; blocksum[i] = run; run += v; }
    }
}

__global__ void k_scan3(const int* __restrict__ in, const int* __restrict__ blockoff,
                        int* out, int N){
    __shared__ int sh[256];
    int tid = threadIdx.x;
    int base = blockIdx.x*1024 + tid*4;
    int e[4]; int s = 0;
    for (int j=0;j<4;j++){ int i = base+j; e[j] = (i < N) ? in[i] : 0; s += e[j]; }
    sh[tid] = s; __syncthreads();
    for (int d=1; d<256; d<<=1){
        int t = (tid >= d) ? sh[tid-d] : 0;
        __syncthreads();
        sh[tid] += t;
        __syncthreads();
    }
    int excl = sh[tid] - s + blockoff[blockIdx.x];
    for (int j=0;j<4;j++){ int i = base+j; if (i < N){ out[i] = excl; excl += e[j]; } }
}

__global__ void k_csrfill(const int* __restrict__ src, const int* __restrict__ dst,
                          const int* __restrict__ row_ptr, int* cursor, int* csr_src, int E){
    int e = blockIdx.x*256 + threadIdx.x;
    if (e < E){
        int d = dst[e];
        int pos = row_ptr[d] + atomicAdd(&cursor[d], 1);
        csr_src[pos] = src[e];
    }
}

// transpose+convert: f32 [K][128] -> bf16 [128][K]
__global__ void k_wt(const float* __restrict__ in, u16* __restrict__ out, int K){
    int i = blockIdx.x*256 + threadIdx.x;
    if (i < K*128){
        int k = i >> 7, n = i & 127;
        out[n*K + k] = f2bf(in[i]);
    }
}

// f32 -> bf16 bulk convert (n4 = count/4)
__global__ void k_f2b(const float* __restrict__ in, u16* __restrict__ out, int n4){
    int i = blockIdx.x*256 + threadIdx.x;
    if (i < n4){
        float4 v = ((const float4*)in)[i];
        ushort4 o;
        o.x = f2bf(v.x); o.y = f2bf(v.y); o.z = f2bf(v.z); o.w = f2bf(v.w);
        ((ushort4*)out)[i] = o;
    }
}

// ---------------- neighbor mean (CSR gather, bf16 h) ----------------

__global__ void k_neigh(const u16* __restrict__ h, const int* __restrict__ row_ptr,
                        const int* __restrict__ indeg, const float* __restrict__ inv_deg,
                        const int* __restrict__ csr_src, u16* __restrict__ neigh, int N){
    int wid  = (blockIdx.x*256 + threadIdx.x) >> 6;
    int lane = threadIdx.x & 63;
    if (wid >= N) return;
    int deg = indeg[wid], start = row_ptr[wid];
    float s0 = 0.f, s1 = 0.f;
    for (int e=0;e<deg;e++){
        int sidx = csr_src[start+e];
        u32 p = *(const u32*)(h + (size_t)sidx*128 + lane*2);
        s0 += bf2f((u16)p);
        s1 += bf2f((u16)(p >> 16));
    }
    float iv = inv_deg[wid];
    u32 o = (u32)f2bf(s0*iv) | ((u32)f2bf(s1*iv) << 16);
    *(u32*)(neigh + (size_t)wid*128 + lane*2) = o;
}

// ---------------- GEMM: C[n_rows,128] = concat-A @ BT^T + bias(f32), fused epilogues ----------------

#define EPI_STORE 0
#define EPI_M     1
#define EPI_GATEV 2
#define EPI_TANH  3

__global__ __launch_bounds__(256) void k_gemm(
    const u16* __restrict__ A0, const u16* __restrict__ A1,
    const u16* __restrict__ BT, const float* __restrict__ bias,
    int n_rows, int n_phases, int epi,
    const u16* E_hs, const float* haspred, const u16* E_h, const u16* E_m,
    u16* C)
{
    __shared__ u16 lA[64][136];
    __shared__ u16 lB[128][136];
    int tid = threadIdx.x;
    int wave = tid >> 6, lane = tid & 63;
    int row0 = blockIdx.x * 64;
    f32x4 acc[8];
    for (int t=0;t<8;t++) acc[t] = (f32x4){0.f,0.f,0.f,0.f};
    int Kstride = 128 * n_phases;

    for (int p=0;p<n_phases;p++){
        const u16* A = p ? A1 : A0;
        // stage A tile: 64 rows x 128 cols bf16 = 1024 x 16B
        for (int i=0;i<4;i++){
            int c = i*256 + tid;
            int r = c >> 4, col8 = (c & 15) * 8;
            u32x4 v = {0,0,0,0};
            if (row0 + r < n_rows)
                v = *(const u32x4*)(A + (size_t)(row0 + r)*128 + col8);
            *(u32x4*)&lA[r][col8] = v;
        }
        // stage BT window: 128 rows x 128 k = 2048 x 16B
        for (int i=0;i<8;i++){
            int c = i*256 + tid;
            int n = c >> 4, col8 = (c & 15) * 8;
            u32x4 v = *(const u32x4*)(BT + (size_t)n*Kstride + p*128 + col8);
            *(u32x4*)&lB[n][col8] = v;
        }
        __syncthreads();
        for (int kk=0;kk<4;kk++){
            int koff = kk*32 + (lane >> 4) * 8;
            bf16x8 a = *(const bf16x8*)&lA[wave*16 + (lane & 15)][koff];
            for (int t=0;t<8;t++){
                bf16x8 b = *(const bf16x8*)&lB[t*16 + (lane & 15)][koff];
                acc[t] = __builtin_amdgcn_mfma_f32_16x16x32_bf16(a, b, acc[t], 0, 0, 0);
            }
        }
        __syncthreads();
    }

    int rbase = wave*16 + ((lane >> 4) << 2);
    for (int t=0;t<8;t++){
        int col = t*16 + (lane & 15);
        float bcol = bias[col];
        for (int r=0;r<4;r++){
            int row = row0 + rbase + r;
            if (row >= n_rows) continue;
            size_t idx = (size_t)row*128 + col;
            float x = acc[t][r] + bcol;
            float out;
            if (epi == EPI_STORE){
                out = x;
            } else if (epi == EPI_M){
                out = bf2f(E_hs[idx]) + haspred[row]*x;
            } else if (epi == EPI_GATEV){
                float g = 1.f/(1.f + expf(-x));
                out = g*bf2f(E_m[idx]) + (1.f - g)*bf2f(E_h[idx]);
            } else {
                out = tanhf(x);
            }
            C[idx] = f2bf(out);
        }
    }
}

// ---------------- LayerNorm + ReLU (wave per node); optional f32 mirror ----------------

__global__ void k_ln(const u16* __restrict__ V, const float* __restrict__ gamma,
                     const float* __restrict__ beta, u16* __restrict__ Hb,
                     float* __restrict__ Hf, int N){
    int wid  = (blockIdx.x*256 + threadIdx.x) >> 6;
    int lane = threadIdx.x & 63;
    if (wid >= N) return;
    u32 p = *(const u32*)(V + (size_t)wid*128 + lane*2);
    float v0 = bf2f((u16)p), v1 = bf2f((u16)(p >> 16));
    float s = v0 + v1;
    for (int o=32;o>0;o>>=1) s += __shfl_xor(s, o);
    float mu = s * (1.f/128.f);
    float d0 = v0 - mu, d1 = v1 - mu;
    float q = d0*d0 + d1*d1;
    for (int o=32;o>0;o>>=1) q += __shfl_xor(q, o);
    float rs = rsqrtf(q*(1.f/128.f) + 1e-5f);
    float g0 = gamma[lane*2], g1 = gamma[lane*2+1];
    float b0 = beta[lane*2],  b1 = beta[lane*2+1];
    float o0 = d0*rs*g0 + b0;
    float o1 = d1*rs*g1 + b1;
    o0 = o0 > 0.f ? o0 : 0.f;
    o1 = o1 > 0.f ? o1 : 0.f;
    *(u32*)(Hb + (size_t)wid*128 + lane*2) = (u32)f2bf(o0) | ((u32)f2bf(o1) << 16);
    if (Hf){
        Hf[(size_t)wid*128 + lane*2]     = o0;
        Hf[(size_t)wid*128 + lane*2 + 1] = o1;
    }
}

// ---------------- attention pooling ----------------

__global__ void k_score(const u16* __restrict__ a, const float* __restrict__ Wsc,
                        const float* __restrict__ bsc, const int* __restrict__ outdeg,
                        float* __restrict__ scores, int N){
    int wid  = (blockIdx.x*256 + threadIdx.x) >> 6;
    int lane = threadIdx.x & 63;
    if (wid >= N) return;
    u32 p = *(const u32*)(a + (size_t)wid*128 + lane*2);
    float s = bf2f((u16)p)*Wsc[lane*2] + bf2f((u16)(p>>16))*Wsc[lane*2+1];
    for (int o=32;o>0;o>>=1) s += __shfl_xor(s, o);
    if (lane == 0){
        s += bsc[0];
        scores[wid] = (outdeg[wid] == 0) ? s : -INFINITY;
    }
}

__global__ void k_max1(const float* __restrict__ scores, float* part, int N){
    __shared__ float sh[256];
    int tid = threadIdx.x;
    float m = -INFINITY;
    for (int i = blockIdx.x*256 + tid; i < N; i += 256*256) m = fmaxf(m, scores[i]);
    sh[tid] = m; __syncthreads();
    for (int d=128; d>0; d>>=1){ if (tid < d) sh[tid] = fmaxf(sh[tid], sh[tid+d]); __syncthreads(); }
    if (tid == 0) part[blockIdx.x] = sh[0];
}

__global__ void k_max2(const float* __restrict__ part, float* gmax){
    __shared__ float sh[256];
    int tid = threadIdx.x;
    sh[tid] = part[tid]; __syncthreads();
    for (int d=128; d>0; d>>=1){ if (tid < d) sh[tid] = fmaxf(sh[tid], sh[tid+d]); __syncthreads(); }
    if (tid == 0) gmax[0] = sh[0];
}

__global__ void k_sum1(const float* __restrict__ scores, const float* __restrict__ gmax,
                       float* part, int N){
    __shared__ float sh[256];
    int tid = threadIdx.x;
    float g = gmax[0];
    float s = 0.f;
    for (int i = blockIdx.x*256 + tid; i < N; i += 256*256){
        float sc = scores[i];
        if (sc != -INFINITY) s += expf(sc - g);
    }
    sh[tid] = s; __syncthreads();
    for (int d=128; d>0; d>>=1){ if (tid < d) sh[tid] += sh[tid+d]; __syncthreads(); }
    if (tid == 0) part[blockIdx.x] = sh[0];
}

__global__ void k_sum2(const float* __restrict__ part, float* invsum){
    __shared__ float sh[256];
    int tid = threadIdx.x;
    sh[tid] = part[tid]; __syncthreads();
    for (int d=128; d>0; d>>=1){ if (tid < d) sh[tid] += sh[tid+d]; __syncthreads(); }
    if (tid == 0) invsum[0] = 1.f / sh[0];
}

__global__ void k_emb1(const u16* __restrict__ h, const float* __restrict__ scores,
                       const float* __restrict__ gmax, float* accum, int N){
    __shared__ float sh[256];
    int tid = threadIdx.x;
    int col = tid & 127, grp = tid >> 7;
    float g = gmax[0];
    float acc = 0.f;
    for (int n = blockIdx.x*2 + grp; n < N; n += 512){
        float s = scores[n];
        if (s != -INFINITY){
            float w = expf(s - g);
            acc += w * bf2f(h[(size_t)n*128 + col]);
        }
    }
    sh[tid] = acc; __syncthreads();
    if (tid < 128) atomicAdd(&accum[col], sh[tid] + sh[tid+128]);
}

__global__ void k_emb2(const float* __restrict__ accum, const float* __restrict__ invsum,
                       float* __restrict__ out){
    int c = threadIdx.x;
    if (c < 128) out[c] = accum[c] * invsum[0];
}

// ---------------- host launch ----------------

extern "C" void kernel_launch(void* const* d_in, const int* in_sizes, int n_in,
                              void* d_out, int out_size, void* d_ws, size_t ws_size,
                              hipStream_t stream)
{
    const float* node_feats = (const float*)d_in[0];
    const int* src     = (const int*)d_in[1];
    const int* dst     = (const int*)d_in[2];
    const float* W_in    = (const float*)d_in[3];
    const float* b_in    = (const float*)d_in[4];
    const float* Ws      = (const float*)d_in[5];
    const float* bs      = (const float*)d_in[6];
    const float* Wn      = (const float*)d_in[7];
    const float* bn      = (const float*)d_in[8];
    const float* Wg      = (const float*)d_in[9];
    const float* bg      = (const float*)d_in[10];
    const float* gamma   = (const float*)d_in[11];
    const float* beta    = (const float*)d_in[12];
    const float* W_att   = (const float*)d_in[13];
    const float* b_att   = (const float*)d_in[14];
    const float* W_score = (const float*)d_in[15];
    const float* b_score = (const float*)d_in[16];

    const int N = in_sizes[0] / 128;
    const int E = in_sizes[1];

    char* w = (char*)d_ws;
    auto alloc = [&](size_t bytes)->char* {
        char* p = w; w += (bytes + 255) & ~(size_t)255; return p;
    };
    u16* WT_in  = (u16*)alloc(128*128*2);
    u16* WT_s   = (u16*)alloc(3*128*128*2);
    u16* WT_n   = (u16*)alloc(3*128*128*2);
    u16* WT_g   = (u16*)alloc(3*128*256*2);
    u16* WT_att = (u16*)alloc(128*128*2);
    int* indeg  = (int*)alloc((size_t)N*4);
    int* outdeg = (int*)alloc((size_t)N*4);
    int* cursor = (int*)alloc((size_t)N*4);
    float* emb_accum = (float*)alloc(128*4);
    size_t zero_bytes = (size_t)((char*)(emb_accum + 128) - (char*)indeg);
    int* row_ptr  = (int*)alloc((size_t)N*4);
    int* blocksum = (int*)alloc(1024*4);
    int* csr_src  = (int*)alloc((size_t)E*4);
    float* inv_deg = (float*)alloc((size_t)N*4);
    float* haspred = (float*)alloc((size_t)N*4);
    float* scores  = (float*)alloc((size_t)N*4);
    float* part    = (float*)alloc(256*4);
    float* gmax    = (float*)alloc(256);
    float* invsum  = (float*)alloc(256);
    u16* buf_h = (u16*)alloc((size_t)N*128*2);
    u16* buf_b = (u16*)alloc((size_t)N*128*2);   // feats_bf16 / neigh / v
    u16* buf_c = (u16*)alloc((size_t)N*128*2);   // hs -> m, then a

    float* h_out   = (float*)d_out;
    float* emb_out = h_out + (size_t)N*128;

    hipMemsetAsync(indeg, 0, zero_bytes, stream);

    k_wt<<<(128*128+255)/256, 256, 0, stream>>>(W_in, WT_in, 128);
    for (int i=0;i<3;i++)
        k_wt<<<(128*128+255)/256, 256, 0, stream>>>(Ws + i*128*128, WT_s + i*16384, 128);
    for (int i=0;i<3;i++)
        k_wt<<<(128*128+255)/256, 256, 0, stream>>>(Wn + i*128*128, WT_n + i*16384, 128);
    for (int i=0;i<3;i++)
        k_wt<<<(256*128+255)/256, 256, 0, stream>>>(Wg + i*256*128, WT_g + i*32768, 256);
    k_wt<<<(128*128+255)/256, 256, 0, stream>>>(W_att, WT_att, 128);

    k_degrees<<<(E+255)/256, 256, 0, stream>>>(src, dst, indeg, outdeg, E);
    k_degaux<<<(N+255)/256, 256, 0, stream>>>(indeg, inv_deg, haspred, N);

    int nb = (N + 1023) / 1024;
    k_scan1<<<nb, 256, 0, stream>>>(indeg, blocksum, N);
    k_scan2<<<1, 256, 0, stream>>>(blocksum, nb);
    k_scan3<<<nb, 256, 0, stream>>>(indeg, blocksum, row_ptr, N);
    k_csrfill<<<(E+255)/256, 256, 0, stream>>>(src, dst, row_ptr, cursor, csr_src, E);

    int gblk = (N + 63) / 64;
    int wblk = (N + 3) / 4;

    // node_feats f32 -> bf16 (into buf_b)
    k_f2b<<<((N*128/4)+255)/256, 256, 0, stream>>>(node_feats, buf_b, N*128/4);

    // h0 = node_feats @ W_in + b_in
    k_gemm<<<gblk, 256, 0, stream>>>(buf_b, nullptr, WT_in, b_in, N, 1, EPI_STORE,
                                     nullptr, nullptr, nullptr, nullptr, buf_h);

    for (int i=0;i<3;i++){
        k_neigh<<<wblk, 256, 0, stream>>>(buf_h, row_ptr, indeg, inv_deg, csr_src, buf_b, N);
        // HS = h @ Ws + bs
        k_gemm<<<gblk, 256, 0, stream>>>(buf_h, nullptr, WT_s + i*16384, bs + i*128, N, 1, EPI_STORE,
                                         nullptr, nullptr, nullptr, nullptr, buf_c);
        // M = HS + haspred*(neigh @ Wn + bn)   (in-place over HS)
        k_gemm<<<gblk, 256, 0, stream>>>(buf_b, nullptr, WT_n + i*16384, bn + i*128, N, 1, EPI_M,
                                         buf_c, haspred, nullptr, nullptr, buf_c);
        // G = h @ Wg_top + M @ Wg_bot + bg; V = sigmoid(G)*M + (1-sigmoid(G))*h
        k_gemm<<<gblk, 256, 0, stream>>>(buf_h, buf_c, WT_g + i*32768, bg + i*128, N, 2, EPI_GATEV,
                                         nullptr, nullptr, buf_h, buf_c, buf_b);
        float* f32out = (i == 2) ? h_out : nullptr;
        k_ln<<<wblk, 256, 0, stream>>>(buf_b, gamma + i*128, beta + i*128, buf_h, f32out, N);
    }

    // a = tanh(h @ W_att + b_att)
    k_gemm<<<gblk, 256, 0, stream>>>(buf_h, nullptr, WT_att, b_att, N, 1, EPI_TANH,
                                     nullptr, nullptr, nullptr, nullptr, buf_c);
    k_score<<<wblk, 256, 0, stream>>>(buf_c, W_score, b_score, outdeg, scores, N);
    k_max1<<<256, 256, 0, stream>>>(scores, part, N);
    k_max2<<<1, 256, 0, stream>>>(part, gmax);
    k_sum1<<<256, 256, 0, stream>>>(scores, gmax, part, N);
    k_sum2<<<1, 256, 0, stream>>>(part, invsum);
    k_emb1<<<256, 256, 0, stream>>>(buf_h, scores, gmax, emb_accum, N);
    k_emb2<<<1, 128, 0, stream>>>(emb_accum, invsum, emb_out);

    (void)n_in; (void)out_size; (void)ws_size;
}

// Round 3
// 697.886 us; speedup vs baseline: 1.7172x; 1.7172x over previous
//
#include <hip/hip_runtime.h>
#include <cmath>

typedef unsigned short u16;
typedef unsigned int   u32;
typedef __attribute__((ext_vector_type(8))) short bf16x8;
typedef __attribute__((ext_vector_type(4))) float f32x4;
typedef __attribute__((ext_vector_type(4))) u32   u32x4;

__device__ __forceinline__ float bf2f(u16 u){
    union { u32 i; float f; } x; x.i = ((u32)u) << 16; return x.f;
}
__device__ __forceinline__ u16 f2bf(float f){
    union { float f; u32 i; } x; x.f = f;
    u32 r = x.i + 0x7fffu + ((x.i >> 16) & 1u);
    return (u16)(r >> 16);
}

// ---------------- graph preprocessing ----------------

__global__ void k_degrees(const int* __restrict__ src, const int* __restrict__ dst,
                          int* indeg, int* outdeg, int E){
    int e = blockIdx.x*256 + threadIdx.x;
    if (e < E){
        atomicAdd(&indeg[dst[e]], 1);
        atomicAdd(&outdeg[src[e]], 1);
    }
}

__global__ void k_degaux(const int* __restrict__ indeg, float* inv_deg, float* haspred, int N){
    int n = blockIdx.x*256 + threadIdx.x;
    if (n < N){
        int d = indeg[n];
        inv_deg[n] = 1.0f / (float)(d > 1 ? d : 1);
        haspred[n] = d > 0 ? 1.0f : 0.0f;
    }
}

__global__ void k_scan1(const int* __restrict__ in, int* blocksum, int N){
    __shared__ int sh[256];
    int tid = threadIdx.x;
    int base = blockIdx.x*1024 + tid*4;
    int s = 0;
    for (int j=0;j<4;j++){ int i = base+j; s += (i < N) ? in[i] : 0; }
    sh[tid] = s; __syncthreads();
    for (int d=128; d>0; d>>=1){ if (tid < d) sh[tid] += sh[tid+d]; __syncthreads(); }
    if (tid == 0) blocksum[blockIdx.x] = sh[0];
}

__global__ void k_scan2(int* blocksum, int nb){
    if (threadIdx.x == 0){
        int run = 0;
        for (int i=0;i<nb;i++){ int v = blocksum[i]; blocksum[i] = run; run += v; }
    }
}

__global__ void k_scan3(const int* __restrict__ in, const int* __restrict__ blockoff,
                        int* out, int N){
    __shared__ int sh[256];
    int tid = threadIdx.x;
    int base = blockIdx.x*1024 + tid*4;
    int e[4]; int s = 0;
    for (int j=0;j<4;j++){ int i = base+j; e[j] = (i < N) ? in[i] : 0; s += e[j]; }
    sh[tid] = s; __syncthreads();
    for (int d=1; d<256; d<<=1){
        int t = (tid >= d) ? sh[tid-d] : 0;
        __syncthreads();
        sh[tid] += t;
        __syncthreads();
    }
    int excl = sh[tid] - s + blockoff[blockIdx.x];
    for (int j=0;j<4;j++){ int i = base+j; if (i < N){ out[i] = excl; excl += e[j]; } }
}

__global__ void k_csrfill(const int* __restrict__ src, const int* __restrict__ dst,
                          const int* __restrict__ row_ptr, int* cursor, int* csr_src, int E){
    int e = blockIdx.x*256 + threadIdx.x;
    if (e < E){
        int d = dst[e];
        int pos = row_ptr[d] + atomicAdd(&cursor[d], 1);
        csr_src[pos] = src[e];
    }
}

// transpose+convert count matrices: f32 [K][128] -> bf16 [128][K]; shift = log2(K*128)
__global__ void k_wt(const float* __restrict__ in, u16* __restrict__ out,
                     int shift, int K, int total){
    int i = blockIdx.x*256 + threadIdx.x;
    if (i < total){
        int mat = i >> shift;
        int within = i & ((1 << shift) - 1);
        int k = within >> 7, n = within & 127;
        out[(size_t)mat*(K*128) + n*K + k] = f2bf(in[i]);
    }
}

// ---------------- neighbor mean: 4 nodes/wave, 16 lanes x 16B per row ----------------

__global__ void k_neigh(const u16* __restrict__ h, const int* __restrict__ row_ptr,
                        const int* __restrict__ indeg, const float* __restrict__ inv_deg,
                        const int* __restrict__ csr_src, u16* __restrict__ neigh, int N){
    int wid  = (blockIdx.x*256 + threadIdx.x) >> 6;
    int lane = threadIdx.x & 63;
    int sub = lane >> 4, sl = lane & 15;
    int node = wid*4 + sub;
    bool valid = node < N;
    int deg   = valid ? indeg[node]   : 0;
    int start = valid ? row_ptr[node] : 0;
    float acc[8] = {0.f,0.f,0.f,0.f,0.f,0.f,0.f,0.f};
    for (int e0 = 0; __any(e0 < deg); e0 += 16){
        int idx = 0;
        if (e0 + sl < deg) idx = csr_src[start + e0 + sl];
        int cnt = deg - e0;
        #pragma unroll
        for (int j = 0; j < 16; j++){
            int sidx = __shfl(idx, (sub << 4) | j);
            if (j < cnt){
                bf16x8 v = *(const bf16x8*)(h + (size_t)sidx*128 + sl*8);
                #pragma unroll
                for (int t=0;t<8;t++) acc[t] += bf2f((u16)v[t]);
            }
        }
    }
    if (valid){
        float iv = inv_deg[node];
        u16 o[8];
        #pragma unroll
        for (int t=0;t<8;t++) o[t] = f2bf(acc[t]*iv);
        *(u32x4*)(neigh + (size_t)node*128 + sl*8) = *(const u32x4*)o;
    }
}

// ---------------- shared GEMM tile machinery ----------------

__device__ __forceinline__ void stage_A_bf16(const u16* __restrict__ A, u16 (*lA)[136],
                                             int row0, int n_rows, int tid){
    #pragma unroll
    for (int i=0;i<4;i++){
        int c = i*256 + tid;
        int r = c >> 4, col8 = (c & 15) * 8;
        u32x4 v = {0,0,0,0};
        if (row0 + r < n_rows)
            v = *(const u32x4*)(A + (size_t)(row0 + r)*128 + col8);
        *(u32x4*)&lA[r][col8] = v;
    }
}

__device__ __forceinline__ void stage_A_f32(const float* __restrict__ A, u16 (*lA)[136],
                                            int row0, int n_rows, int tid){
    #pragma unroll
    for (int i=0;i<4;i++){
        int c = i*256 + tid;
        int r = c >> 4, col8 = (c & 15) * 8;
        u16 o[8] = {0,0,0,0,0,0,0,0};
        if (row0 + r < n_rows){
            float4 v0 = *(const float4*)(A + (size_t)(row0 + r)*128 + col8);
            float4 v1 = *(const float4*)(A + (size_t)(row0 + r)*128 + col8 + 4);
            o[0]=f2bf(v0.x); o[1]=f2bf(v0.y); o[2]=f2bf(v0.z); o[3]=f2bf(v0.w);
            o[4]=f2bf(v1.x); o[5]=f2bf(v1.y); o[6]=f2bf(v1.z); o[7]=f2bf(v1.w);
        }
        *(u32x4*)&lA[r][col8] = *(const u32x4*)o;
    }
}

__device__ __forceinline__ void stage_B(const u16* __restrict__ BT, int Ks, int koff0,
                                        u16 (*lB)[136], int tid){
    #pragma unroll
    for (int i=0;i<8;i++){
        int c = i*256 + tid;
        int n = c >> 4, col8 = (c & 15) * 8;
        u32x4 v = *(const u32x4*)(BT + (size_t)n*Ks + koff0 + col8);
        *(u32x4*)&lB[n][col8] = v;
    }
}

__device__ __forceinline__ void mfma_tile(const u16 (*lA)[136], const u16 (*lB)[136],
                                          int wave, int lane, f32x4* acc){
    #pragma unroll
    for (int kk=0;kk<4;kk++){
        int koff = kk*32 + (lane >> 4) * 8;
        bf16x8 a = *(const bf16x8*)&lA[wave*16 + (lane & 15)][koff];
        #pragma unroll
        for (int t=0;t<8;t++){
            bf16x8 b = *(const bf16x8*)&lB[t*16 + (lane & 15)][koff];
            acc[t] = __builtin_amdgcn_mfma_f32_16x16x32_bf16(a, b, acc[t], 0, 0, 0);
        }
    }
}

// ---------------- GEMM: h0 = f32 feats @ W_in + b_in -> bf16 ----------------

__global__ __launch_bounds__(256) void k_gemm_in(
    const float* __restrict__ A, const u16* __restrict__ BT,
    const float* __restrict__ bias, u16* __restrict__ C, int n_rows)
{
    __shared__ u16 lA[64][136];
    __shared__ u16 lB[128][136];
    int tid = threadIdx.x, wave = tid >> 6, lane = tid & 63;
    int row0 = blockIdx.x * 64;
    f32x4 acc[8];
    #pragma unroll
    for (int t=0;t<8;t++) acc[t] = (f32x4){0.f,0.f,0.f,0.f};
    stage_A_f32(A, lA, row0, n_rows, tid);
    stage_B(BT, 128, 0, lB, tid);
    __syncthreads();
    mfma_tile(lA, lB, wave, lane, acc);

    int sl = lane & 15;
    int rbase = wave*16 + (lane >> 4)*4;
    float bc[8];
    #pragma unroll
    for (int t=0;t<8;t++) bc[t] = bias[t*16 + sl];
    for (int r=0;r<4;r++){
        int row = row0 + rbase + r;
        if (row >= n_rows) continue;
        #pragma unroll
        for (int t=0;t<8;t++)
            C[(size_t)row*128 + t*16 + sl] = f2bf(acc[t][r] + bc[t]);
    }
}

// ---------------- GEMM: M = h@Ws + bs + haspred*(neigh@Wn + bn) ----------------

__global__ __launch_bounds__(256) void k_gemm_m(
    const u16* __restrict__ H, const u16* __restrict__ Ng,
    const u16* __restrict__ BsT, const u16* __restrict__ BnT,
    const float* __restrict__ bs, const float* __restrict__ bn,
    const float* __restrict__ haspred, u16* __restrict__ C, int n_rows)
{
    __shared__ u16 lA[64][136];
    __shared__ u16 lB[128][136];
    int tid = threadIdx.x, wave = tid >> 6, lane = tid & 63;
    int row0 = blockIdx.x * 64;
    f32x4 acc[8], acc2[8];
    #pragma unroll
    for (int t=0;t<8;t++){ acc[t] = (f32x4){0.f,0.f,0.f,0.f}; acc2[t] = (f32x4){0.f,0.f,0.f,0.f}; }

    stage_A_bf16(H, lA, row0, n_rows, tid);
    stage_B(BsT, 128, 0, lB, tid);
    __syncthreads();
    mfma_tile(lA, lB, wave, lane, acc);
    __syncthreads();
    stage_A_bf16(Ng, lA, row0, n_rows, tid);
    stage_B(BnT, 128, 0, lB, tid);
    __syncthreads();
    mfma_tile(lA, lB, wave, lane, acc2);

    int sl = lane & 15;
    int rbase = wave*16 + (lane >> 4)*4;
    float bsc[8], bnc[8];
    #pragma unroll
    for (int t=0;t<8;t++){ bsc[t] = bs[t*16 + sl]; bnc[t] = bn[t*16 + sl]; }
    for (int r=0;r<4;r++){
        int row = row0 + rbase + r;
        if (row >= n_rows) continue;
        float hp = haspred[row];
        #pragma unroll
        for (int t=0;t<8;t++){
            float m = acc[t][r] + bsc[t] + hp*(acc2[t][r] + bnc[t]);
            C[(size_t)row*128 + t*16 + sl] = f2bf(m);
        }
    }
}

// ------- GEMM: gate = sigmoid([h,m]@Wg + bg); v = gate*m+(1-g)*h; LN; ReLU -------

__global__ __launch_bounds__(256) void k_gemm_gln(
    const u16* __restrict__ H, const u16* __restrict__ M,
    const u16* __restrict__ BT, const float* __restrict__ bg,
    const float* __restrict__ gamma, const float* __restrict__ beta,
    u16* __restrict__ Hb, float* __restrict__ Hf, int n_rows)
{
    __shared__ u16 lA[64][136];
    __shared__ u16 lB[128][136];
    int tid = threadIdx.x, wave = tid >> 6, lane = tid & 63;
    int row0 = blockIdx.x * 64;
    f32x4 acc[8];
    #pragma unroll
    for (int t=0;t<8;t++) acc[t] = (f32x4){0.f,0.f,0.f,0.f};

    stage_A_bf16(H, lA, row0, n_rows, tid);
    stage_B(BT, 256, 0, lB, tid);
    __syncthreads();
    mfma_tile(lA, lB, wave, lane, acc);
    __syncthreads();
    stage_A_bf16(M, lA, row0, n_rows, tid);
    stage_B(BT, 256, 128, lB, tid);
    __syncthreads();
    mfma_tile(lA, lB, wave, lane, acc);

    int sl = lane & 15;
    int rbase = wave*16 + (lane >> 4)*4;
    float bgc[8], gam[8], bet[8];
    #pragma unroll
    for (int t=0;t<8;t++){
        int col = t*16 + sl;
        bgc[t] = bg[col]; gam[t] = gamma[col]; bet[t] = beta[col];
    }
    for (int r=0;r<4;r++){
        int row = row0 + rbase + r;
        if (row >= n_rows) continue;   // quad-uniform: row depends only on (wave,quad,r)
        float v[8], s = 0.f;
        #pragma unroll
        for (int t=0;t<8;t++){
            size_t idx = (size_t)row*128 + t*16 + sl;
            float x = acc[t][r] + bgc[t];
            float g = 1.f/(1.f + expf(-x));
            float hv = bf2f(H[idx]), mv = bf2f(M[idx]);
            v[t] = g*mv + (1.f - g)*hv;
            s += v[t];
        }
        s += __shfl_xor(s,1); s += __shfl_xor(s,2); s += __shfl_xor(s,4); s += __shfl_xor(s,8);
        float mu = s * (1.f/128.f);
        float q = 0.f;
        #pragma unroll
        for (int t=0;t<8;t++){ float d = v[t]-mu; q += d*d; }
        q += __shfl_xor(q,1); q += __shfl_xor(q,2); q += __shfl_xor(q,4); q += __shfl_xor(q,8);
        float rs = rsqrtf(q*(1.f/128.f) + 1e-5f);
        #pragma unroll
        for (int t=0;t<8;t++){
            size_t idx = (size_t)row*128 + t*16 + sl;
            float o = (v[t]-mu)*rs*gam[t] + bet[t];
            o = o > 0.f ? o : 0.f;
            Hb[idx] = f2bf(o);
            if (Hf) Hf[idx] = o;
        }
    }
}

// ------- GEMM: scores = sinkmask( tanh(h@W_att+b_att) @ W_score + b_score ) -------

__global__ __launch_bounds__(256) void k_gemm_att(
    const u16* __restrict__ H, const u16* __restrict__ BT,
    const float* __restrict__ b_att, const float* __restrict__ Wsc,
    const float* __restrict__ bsc, const int* __restrict__ outdeg,
    float* __restrict__ scores, int n_rows)
{
    __shared__ u16 lA[64][136];
    __shared__ u16 lB[128][136];
    int tid = threadIdx.x, wave = tid >> 6, lane = tid & 63;
    int row0 = blockIdx.x * 64;
    f32x4 acc[8];
    #pragma unroll
    for (int t=0;t<8;t++) acc[t] = (f32x4){0.f,0.f,0.f,0.f};
    stage_A_bf16(H, lA, row0, n_rows, tid);
    stage_B(BT, 128, 0, lB, tid);
    __syncthreads();
    mfma_tile(lA, lB, wave, lane, acc);

    int sl = lane & 15;
    int rbase = wave*16 + (lane >> 4)*4;
    float bac[8], wc[8];
    #pragma unroll
    for (int t=0;t<8;t++){ bac[t] = b_att[t*16 + sl]; wc[t] = Wsc[t*16 + sl]; }
    float b0 = bsc[0];
    for (int r=0;r<4;r++){
        int row = row0 + rbase + r;
        if (row >= n_rows) continue;
        float p = 0.f;
        #pragma unroll
        for (int t=0;t<8;t++) p += tanhf(acc[t][r] + bac[t]) * wc[t];
        p += __shfl_xor(p,1); p += __shfl_xor(p,2); p += __shfl_xor(p,4); p += __shfl_xor(p,8);
        if (sl == 0)
            scores[row] = (outdeg[row] == 0) ? (p + b0) : -INFINITY;
    }
}

// ---------------- softmax-pool over sinks (no max: |score| <= ~5) ----------------

__global__ void k_sum1(const float* __restrict__ scores, float* part, int N){
    __shared__ float sh[256];
    int tid = threadIdx.x;
    float s = 0.f;
    for (int i = blockIdx.x*256 + tid; i < N; i += 256*256) s += expf(scores[i]);
    sh[tid] = s; __syncthreads();
    for (int d=128; d>0; d>>=1){ if (tid < d) sh[tid] += sh[tid+d]; __syncthreads(); }
    if (tid == 0) part[blockIdx.x] = sh[0];
}

__global__ void k_sum2(const float* __restrict__ part, float* invsum){
    __shared__ float sh[256];
    int tid = threadIdx.x;
    sh[tid] = part[tid]; __syncthreads();
    for (int d=128; d>0; d>>=1){ if (tid < d) sh[tid] += sh[tid+d]; __syncthreads(); }
    if (tid == 0) invsum[0] = 1.f / sh[0];
}

__global__ void k_emb1(const u16* __restrict__ h, const float* __restrict__ scores,
                       float* accum, int N){
    __shared__ float sh[256];
    int tid = threadIdx.x;
    int col = tid & 127, grp = tid >> 7;
    float acc = 0.f;
    for (int n = blockIdx.x*2 + grp; n < N; n += 512){
        float s = scores[n];
        if (s > -1e30f){
            float w = expf(s);
            acc += w * bf2f(h[(size_t)n*128 + col]);
        }
    }
    sh[tid] = acc; __syncthreads();
    if (tid < 128) atomicAdd(&accum[col], sh[tid] + sh[tid+128]);
}

__global__ void k_emb2(const float* __restrict__ accum, const float* __restrict__ invsum,
                       float* __restrict__ out){
    int c = threadIdx.x;
    if (c < 128) out[c] = accum[c] * invsum[0];
}

// ---------------- host launch ----------------

extern "C" void kernel_launch(void* const* d_in, const int* in_sizes, int n_in,
                              void* d_out, int out_size, void* d_ws, size_t ws_size,
                              hipStream_t stream)
{
    const float* node_feats = (const float*)d_in[0];
    const int* src     = (const int*)d_in[1];
    const int* dst     = (const int*)d_in[2];
    const float* W_in    = (const float*)d_in[3];
    const float* b_in    = (const float*)d_in[4];
    const float* Ws      = (const float*)d_in[5];
    const float* bs      = (const float*)d_in[6];
    const float* Wn      = (const float*)d_in[7];
    const float* bn      = (const float*)d_in[8];
    const float* Wg      = (const float*)d_in[9];
    const float* bg      = (const float*)d_in[10];
    const float* gamma   = (const float*)d_in[11];
    const float* beta    = (const float*)d_in[12];
    const float* W_att   = (const float*)d_in[13];
    const float* b_att   = (const float*)d_in[14];
    const float* W_score = (const float*)d_in[15];
    const float* b_score = (const float*)d_in[16];

    const int N = in_sizes[0] / 128;
    const int E = in_sizes[1];

    char* w = (char*)d_ws;
    auto alloc = [&](size_t bytes)->char* {
        char* p = w; w += (bytes + 255) & ~(size_t)255; return p;
    };
    u16* WT_in  = (u16*)alloc(128*128*2);
    u16* WT_s   = (u16*)alloc(3*128*128*2);
    u16* WT_n   = (u16*)alloc(3*128*128*2);
    u16* WT_g   = (u16*)alloc(3*128*256*2);
    u16* WT_att = (u16*)alloc(128*128*2);
    int* indeg  = (int*)alloc((size_t)N*4);
    int* outdeg = (int*)alloc((size_t)N*4);
    int* cursor = (int*)alloc((size_t)N*4);
    float* emb_accum = (float*)alloc(128*4);
    size_t zero_bytes = (size_t)((char*)(emb_accum + 128) - (char*)indeg);
    int* row_ptr  = (int*)alloc((size_t)N*4);
    int* blocksum = (int*)alloc(1024*4);
    int* csr_src  = (int*)alloc((size_t)E*4);
    float* inv_deg = (float*)alloc((size_t)N*4);
    float* haspred = (float*)alloc((size_t)N*4);
    float* scores  = (float*)alloc((size_t)N*4);
    float* part    = (float*)alloc(256*4);
    float* invsum  = (float*)alloc(256);
    u16* buf_h = (u16*)alloc((size_t)N*128*2);   // h (updated in place per layer)
    u16* buf_b = (u16*)alloc((size_t)N*128*2);   // neigh
    u16* buf_c = (u16*)alloc((size_t)N*128*2);   // m

    float* h_out   = (float*)d_out;
    float* emb_out = h_out + (size_t)N*128;

    hipMemsetAsync(indeg, 0, zero_bytes, stream);

    k_wt<<<(16384  +255)/256, 256, 0, stream>>>(W_in,  WT_in,  14, 128, 16384);
    k_wt<<<(49152  +255)/256, 256, 0, stream>>>(Ws,    WT_s,   14, 128, 49152);
    k_wt<<<(49152  +255)/256, 256, 0, stream>>>(Wn,    WT_n,   14, 128, 49152);
    k_wt<<<(98304  +255)/256, 256, 0, stream>>>(Wg,    WT_g,   15, 256, 98304);
    k_wt<<<(16384  +255)/256, 256, 0, stream>>>(W_att, WT_att, 14, 128, 16384);

    k_degrees<<<(E+255)/256, 256, 0, stream>>>(src, dst, indeg, outdeg, E);
    k_degaux<<<(N+255)/256, 256, 0, stream>>>(indeg, inv_deg, haspred, N);

    int nb = (N + 1023) / 1024;
    k_scan1<<<nb, 256, 0, stream>>>(indeg, blocksum, N);
    k_scan2<<<1, 256, 0, stream>>>(blocksum, nb);
    k_scan3<<<nb, 256, 0, stream>>>(indeg, blocksum, row_ptr, N);
    k_csrfill<<<(E+255)/256, 256, 0, stream>>>(src, dst, row_ptr, cursor, csr_src, E);

    int gblk = (N + 63) / 64;
    int nblk = (N + 15) / 16;

    k_gemm_in<<<gblk, 256, 0, stream>>>(node_feats, WT_in, b_in, buf_h, N);

    for (int i=0;i<3;i++){
        k_neigh<<<nblk, 256, 0, stream>>>(buf_h, row_ptr, indeg, inv_deg, csr_src, buf_b, N);
        k_gemm_m<<<gblk, 256, 0, stream>>>(buf_h, buf_b, WT_s + i*16384, WT_n + i*16384,
                                           bs + i*128, bn + i*128, haspred, buf_c, N);
        float* f32out = (i == 2) ? h_out : nullptr;
        k_gemm_gln<<<gblk, 256, 0, stream>>>(buf_h, buf_c, WT_g + i*32768, bg + i*128,
                                             gamma + i*128, beta + i*128,
                                             buf_h, f32out, N);
    }

    k_gemm_att<<<gblk, 256, 0, stream>>>(buf_h, WT_att, b_att, W_score, b_score,
                                         outdeg, scores, N);
    k_sum1<<<256, 256, 0, stream>>>(scores, part, N);
    k_sum2<<<1, 256, 0, stream>>>(part, invsum);
    k_emb1<<<256, 256, 0, stream>>>(buf_h, scores, emb_accum, N);
    k_emb2<<<1, 128, 0, stream>>>(emb_accum, invsum, emb_out);

    (void)n_in; (void)out_size; (void)ws_size;
}

// Round 4
// 627.591 us; speedup vs baseline: 1.9095x; 1.1120x over previous
//
#include <hip/hip_runtime.h>
#include <cmath>

typedef unsigned short u16;
typedef unsigned int   u32;
typedef __attribute__((ext_vector_type(8))) short bf16x8;
typedef __attribute__((ext_vector_type(4))) float f32x4;
typedef __attribute__((ext_vector_type(4))) u32   u32x4;

__device__ __forceinline__ float bf2f(u16 u){
    union { u32 i; float f; } x; x.i = ((u32)u) << 16; return x.f;
}
__device__ __forceinline__ u16 f2bf(float f){
    union { float f; u32 i; } x; x.f = f;
    u32 r = x.i + 0x7fffu + ((x.i >> 16) & 1u);
    return (u16)(r >> 16);
}

// ---------------- graph preprocessing ----------------

// count indegrees (returning within-row slot), mark non-sinks
__global__ void k_count(const int* __restrict__ src, const int* __restrict__ dst,
                        int* cnt, int* notsink, int* pos, int E){
    int e = blockIdx.x*256 + threadIdx.x;
    if (e < E){
        pos[e] = atomicAdd(&cnt[dst[e]], 1);
        notsink[src[e]] = 1;   // benign race: all writers store 1
    }
}

__global__ void k_scan1(const int* __restrict__ in, int* blocksum, int N){
    __shared__ int sh[256];
    int tid = threadIdx.x;
    int base = blockIdx.x*1024 + tid*4;
    int s = 0;
    for (int j=0;j<4;j++){ int i = base+j; s += (i < N) ? in[i] : 0; }
    sh[tid] = s; __syncthreads();
    for (int d=128; d>0; d>>=1){ if (tid < d) sh[tid] += sh[tid+d]; __syncthreads(); }
    if (tid == 0) blocksum[blockIdx.x] = sh[0];
}

__global__ void k_scan2(int* blocksum, int nb){
    if (threadIdx.x == 0){
        int run = 0;
        for (int i=0;i<nb;i++){ int v = blocksum[i]; blocksum[i] = run; run += v; }
    }
}

// exclusive scan -> row_ptr; also emit inv_deg / haspred
__global__ void k_scan3(const int* __restrict__ in, const int* __restrict__ blockoff,
                        int* out, float* inv_deg, float* haspred, int N){
    __shared__ int sh[256];
    int tid = threadIdx.x;
    int base = blockIdx.x*1024 + tid*4;
    int e[4]; int s = 0;
    for (int j=0;j<4;j++){ int i = base+j; e[j] = (i < N) ? in[i] : 0; s += e[j]; }
    sh[tid] = s; __syncthreads();
    for (int d=1; d<256; d<<=1){
        int t = (tid >= d) ? sh[tid-d] : 0;
        __syncthreads();
        sh[tid] += t;
        __syncthreads();
    }
    int excl = sh[tid] - s + blockoff[blockIdx.x];
    for (int j=0;j<4;j++){
        int i = base+j;
        if (i < N){
            out[i] = excl; excl += e[j];
            inv_deg[i] = 1.0f / (float)(e[j] > 1 ? e[j] : 1);
            haspred[i] = e[j] > 0 ? 1.0f : 0.0f;
        }
    }
}

// atomic-free CSR fill using precomputed slots
__global__ void k_place(const int* __restrict__ src, const int* __restrict__ dst,
                        const int* __restrict__ row_ptr, const int* __restrict__ pos,
                        int* csr_src, int E){
    int e = blockIdx.x*256 + threadIdx.x;
    if (e < E)
        csr_src[row_ptr[dst[e]] + pos[e]] = src[e];
}

// transpose+convert weight matrices: f32 [K][128] -> bf16 [128][K]; shift = log2(K*128)
__global__ void k_wt(const float* __restrict__ in, u16* __restrict__ out,
                     int shift, int K, int total){
    int i = blockIdx.x*256 + threadIdx.x;
    if (i < total){
        int mat = i >> shift;
        int within = i & ((1 << shift) - 1);
        int k = within >> 7, n = within & 127;
        out[(size_t)mat*(K*128) + n*K + k] = f2bf(in[i]);
    }
}

// ---------------- neighbor mean: 4 nodes/wave, 16 lanes x 16B per row ----------------

__global__ void k_neigh(const u16* __restrict__ h, const int* __restrict__ row_ptr,
                        const int* __restrict__ indeg, const float* __restrict__ inv_deg,
                        const int* __restrict__ csr_src, u16* __restrict__ neigh, int N){
    int wid  = (blockIdx.x*256 + threadIdx.x) >> 6;
    int lane = threadIdx.x & 63;
    int sub = lane >> 4, sl = lane & 15;
    int node = wid*4 + sub;
    bool valid = node < N;
    int deg   = valid ? indeg[node]   : 0;
    int start = valid ? row_ptr[node] : 0;
    float acc[8] = {0.f,0.f,0.f,0.f,0.f,0.f,0.f,0.f};
    for (int e0 = 0; __any(e0 < deg); e0 += 16){
        int idx = 0;
        if (e0 + sl < deg) idx = csr_src[start + e0 + sl];
        int cnt = deg - e0;
        #pragma unroll
        for (int j = 0; j < 16; j++){
            int sidx = __shfl(idx, (sub << 4) | j);
            if (j < cnt){
                bf16x8 v = *(const bf16x8*)(h + (size_t)sidx*128 + sl*8);
                #pragma unroll
                for (int t=0;t<8;t++) acc[t] += bf2f((u16)v[t]);
            }
        }
    }
    if (valid){
        float iv = inv_deg[node];
        u16 o[8];
        #pragma unroll
        for (int t=0;t<8;t++) o[t] = f2bf(acc[t]*iv);
        *(u32x4*)(neigh + (size_t)node*128 + sl*8) = *(const u32x4*)o;
    }
}

// ---------------- shared GEMM tile machinery ----------------

__device__ __forceinline__ void stage_A_bf16(const u16* __restrict__ A, u16 (*lA)[136],
                                             int row0, int n_rows, int tid){
    #pragma unroll
    for (int i=0;i<4;i++){
        int c = i*256 + tid;
        int r = c >> 4, col8 = (c & 15) * 8;
        u32x4 v = {0,0,0,0};
        if (row0 + r < n_rows)
            v = *(const u32x4*)(A + (size_t)(row0 + r)*128 + col8);
        *(u32x4*)&lA[r][col8] = v;
    }
}

__device__ __forceinline__ void stage_A_f32(const float* __restrict__ A, u16 (*lA)[136],
                                            int row0, int n_rows, int tid){
    #pragma unroll
    for (int i=0;i<4;i++){
        int c = i*256 + tid;
        int r = c >> 4, col8 = (c & 15) * 8;
        u16 o[8] = {0,0,0,0,0,0,0,0};
        if (row0 + r < n_rows){
            float4 v0 = *(const float4*)(A + (size_t)(row0 + r)*128 + col8);
            float4 v1 = *(const float4*)(A + (size_t)(row0 + r)*128 + col8 + 4);
            o[0]=f2bf(v0.x); o[1]=f2bf(v0.y); o[2]=f2bf(v0.z); o[3]=f2bf(v0.w);
            o[4]=f2bf(v1.x); o[5]=f2bf(v1.y); o[6]=f2bf(v1.z); o[7]=f2bf(v1.w);
        }
        *(u32x4*)&lA[r][col8] = *(const u32x4*)o;
    }
}

// full-K B stage: 128 cols x 128 k
__device__ __forceinline__ void stage_B(const u16* __restrict__ BT, int Ks, int koff0,
                                        u16 (*lB)[136], int tid){
    #pragma unroll
    for (int i=0;i<8;i++){
        int c = i*256 + tid;
        int n = c >> 4, col8 = (c & 15) * 8;
        u32x4 v = *(const u32x4*)(BT + (size_t)n*Ks + koff0 + col8);
        *(u32x4*)&lB[n][col8] = v;
    }
}

// half-K B stage: 128 cols x 64 k window starting at koff0
__device__ __forceinline__ void stage_B_half(const u16* __restrict__ BT, int Ks, int koff0,
                                             u16 (*lB)[72], int tid){
    #pragma unroll
    for (int i=0;i<4;i++){
        int c = i*256 + tid;
        int n = c >> 3, col8 = (c & 7) * 8;
        *(u32x4*)&lB[n][col8] = *(const u32x4*)(BT + (size_t)n*Ks + koff0 + col8);
    }
}

__device__ __forceinline__ void mfma_tile(const u16 (*lA)[136], const u16 (*lB)[136],
                                          int wave, int lane, f32x4* acc){
    #pragma unroll
    for (int kk=0;kk<4;kk++){
        int koff = kk*32 + (lane >> 4) * 8;
        bf16x8 a = *(const bf16x8*)&lA[wave*16 + (lane & 15)][koff];
        #pragma unroll
        for (int t=0;t<8;t++){
            bf16x8 b = *(const bf16x8*)&lB[t*16 + (lane & 15)][koff];
            acc[t] = __builtin_amdgcn_mfma_f32_16x16x32_bf16(a, b, acc[t], 0, 0, 0);
        }
    }
}

// A read at absolute k = kbaseA + (window k); B read within its 64-k window
__device__ __forceinline__ void mfma_half(const u16 (*lA)[136], const u16 (*lB)[72],
                                          int wave, int lane, int kbaseA, f32x4* acc){
    #pragma unroll
    for (int kk=0;kk<2;kk++){
        int kw = kk*32 + (lane >> 4) * 8;
        bf16x8 a = *(const bf16x8*)&lA[wave*16 + (lane & 15)][kbaseA + kw];
        #pragma unroll
        for (int t=0;t<8;t++){
            bf16x8 b = *(const bf16x8*)&lB[t*16 + (lane & 15)][kw];
            acc[t] = __builtin_amdgcn_mfma_f32_16x16x32_bf16(a, b, acc[t], 0, 0, 0);
        }
    }
}

// ---------------- GEMM: h0 = f32 feats @ W_in + b_in -> bf16 ----------------

__global__ __launch_bounds__(256) void k_gemm_in(
    const float* __restrict__ A, const u16* __restrict__ BT,
    const float* __restrict__ bias, u16* __restrict__ C, int n_rows)
{
    __shared__ u16 lA[64][136];
    __shared__ u16 lB[128][136];
    int tid = threadIdx.x, wave = tid >> 6, lane = tid & 63;
    int row0 = blockIdx.x * 64;
    f32x4 acc[8];
    #pragma unroll
    for (int t=0;t<8;t++) acc[t] = (f32x4){0.f,0.f,0.f,0.f};
    stage_A_f32(A, lA, row0, n_rows, tid);
    stage_B(BT, 128, 0, lB, tid);
    __syncthreads();
    mfma_tile(lA, lB, wave, lane, acc);

    int sl = lane & 15;
    int rbase = wave*16 + (lane >> 4)*4;
    float bc[8];
    #pragma unroll
    for (int t=0;t<8;t++) bc[t] = bias[t*16 + sl];
    for (int r=0;r<4;r++){
        int row = row0 + rbase + r;
        if (row >= n_rows) continue;
        #pragma unroll
        for (int t=0;t<8;t++)
            C[(size_t)row*128 + t*16 + sl] = f2bf(acc[t][r] + bc[t]);
    }
}

// -------- fused layer: M = h@Ws+bs+hp*(ng@Wn+bn); g=sig([h,M]@Wg+bg);
//          v = g*M+(1-g)*h; LayerNorm; ReLU --------

__global__ __launch_bounds__(256) void k_layer(
    const u16* __restrict__ H, const u16* __restrict__ Ng,
    const u16* __restrict__ BsT, const u16* __restrict__ BnT,
    const u16* __restrict__ BgT,
    const float* __restrict__ bs, const float* __restrict__ bn,
    const float* __restrict__ bg,
    const float* __restrict__ gamma, const float* __restrict__ beta,
    const float* __restrict__ haspred,
    u16* __restrict__ Hb, float* __restrict__ Hf, int n_rows)
{
    __shared__ u16 lA[64][136];   // H tile (persists whole kernel)
    __shared__ u16 lM[64][136];   // Ng tile, then M tile
    __shared__ u16 lB[128][72];   // half-K weight window
    int tid = threadIdx.x, wave = tid >> 6, lane = tid & 63;
    int sl = lane & 15;
    int row0 = blockIdx.x * 64;
    f32x4 accs[8], accn[8];
    #pragma unroll
    for (int t=0;t<8;t++){ accs[t] = (f32x4){0.f,0.f,0.f,0.f}; accn[t] = (f32x4){0.f,0.f,0.f,0.f}; }

    // phase 1: h @ Ws
    stage_A_bf16(H, lA, row0, n_rows, tid);
    stage_B_half(BsT, 128, 0, lB, tid);
    __syncthreads();
    mfma_half(lA, lB, wave, lane, 0, accs);
    __syncthreads();
    stage_B_half(BsT, 128, 64, lB, tid);
    __syncthreads();
    mfma_half(lA, lB, wave, lane, 64, accs);
    __syncthreads();

    // phase 2: ng @ Wn
    stage_A_bf16(Ng, lM, row0, n_rows, tid);
    stage_B_half(BnT, 128, 0, lB, tid);
    __syncthreads();
    mfma_half(lM, lB, wave, lane, 0, accn);
    __syncthreads();
    stage_B_half(BnT, 128, 64, lB, tid);
    __syncthreads();
    mfma_half(lM, lB, wave, lane, 64, accn);
    __syncthreads();

    // build M in LDS (C-layout write)
    int rbase = wave*16 + (lane >> 4)*4;
    {
        float bsc[8], bnc[8];
        #pragma unroll
        for (int t=0;t<8;t++){ bsc[t] = bs[t*16 + sl]; bnc[t] = bn[t*16 + sl]; }
        #pragma unroll
        for (int r=0;r<4;r++){
            int row = row0 + rbase + r;
            float hp = (row < n_rows) ? haspred[row] : 0.f;
            #pragma unroll
            for (int t=0;t<8;t++){
                float m = accs[t][r] + bsc[t] + hp*(accn[t][r] + bnc[t]);
                lM[rbase + r][t*16 + sl] = f2bf(m);
            }
        }
    }
    __syncthreads();

    // phase 3: gate = h @ Wg_top + M @ Wg_bot  (reuse accs)
    #pragma unroll
    for (int t=0;t<8;t++) accs[t] = (f32x4){0.f,0.f,0.f,0.f};
    stage_B_half(BgT, 256, 0, lB, tid);
    __syncthreads();
    mfma_half(lA, lB, wave, lane, 0, accs);
    __syncthreads();
    stage_B_half(BgT, 256, 64, lB, tid);
    __syncthreads();
    mfma_half(lA, lB, wave, lane, 64, accs);
    __syncthreads();
    stage_B_half(BgT, 256, 128, lB, tid);
    __syncthreads();
    mfma_half(lM, lB, wave, lane, 0, accs);
    __syncthreads();
    stage_B_half(BgT, 256, 192, lB, tid);
    __syncthreads();
    mfma_half(lM, lB, wave, lane, 64, accs);
    __syncthreads();

    // epilogue: gate, blend, LayerNorm, ReLU
    float bgc[8], gam[8], bet[8];
    #pragma unroll
    for (int t=0;t<8;t++){
        int col = t*16 + sl;
        bgc[t] = bg[col]; gam[t] = gamma[col]; bet[t] = beta[col];
    }
    for (int r=0;r<4;r++){
        int row = row0 + rbase + r;
        if (row >= n_rows) continue;   // quad-uniform
        float v[8], s = 0.f;
        #pragma unroll
        for (int t=0;t<8;t++){
            int col = t*16 + sl;
            float x = accs[t][r] + bgc[t];
            float g = 1.f/(1.f + expf(-x));
            float hv = bf2f(H[(size_t)row*128 + col]);      // L2-hot
            float mv = bf2f(lM[rbase + r][col]);            // from LDS
            v[t] = g*mv + (1.f - g)*hv;
            s += v[t];
        }
        s += __shfl_xor(s,1); s += __shfl_xor(s,2); s += __shfl_xor(s,4); s += __shfl_xor(s,8);
        float mu = s * (1.f/128.f);
        float q = 0.f;
        #pragma unroll
        for (int t=0;t<8;t++){ float d = v[t]-mu; q += d*d; }
        q += __shfl_xor(q,1); q += __shfl_xor(q,2); q += __shfl_xor(q,4); q += __shfl_xor(q,8);
        float rs = rsqrtf(q*(1.f/128.f) + 1e-5f);
        #pragma unroll
        for (int t=0;t<8;t++){
            size_t idx = (size_t)row*128 + t*16 + sl;
            float o = (v[t]-mu)*rs*gam[t] + bet[t];
            o = o > 0.f ? o : 0.f;
            Hb[idx] = f2bf(o);
            if (Hf) Hf[idx] = o;
        }
    }
}

// ------- GEMM: scores = sinkmask( tanh(h@W_att+b_att) @ W_score + b_score ) -------

__global__ __launch_bounds__(256) void k_gemm_att(
    const u16* __restrict__ H, const u16* __restrict__ BT,
    const float* __restrict__ b_att, const float* __restrict__ Wsc,
    const float* __restrict__ bsc, const int* __restrict__ notsink,
    float* __restrict__ scores, int n_rows)
{
    __shared__ u16 lA[64][136];
    __shared__ u16 lB[128][136];
    int tid = threadIdx.x, wave = tid >> 6, lane = tid & 63;
    int row0 = blockIdx.x * 64;
    f32x4 acc[8];
    #pragma unroll
    for (int t=0;t<8;t++) acc[t] = (f32x4){0.f,0.f,0.f,0.f};
    stage_A_bf16(H, lA, row0, n_rows, tid);
    stage_B(BT, 128, 0, lB, tid);
    __syncthreads();
    mfma_tile(lA, lB, wave, lane, acc);

    int sl = lane & 15;
    int rbase = wave*16 + (lane >> 4)*4;
    float bac[8], wc[8];
    #pragma unroll
    for (int t=0;t<8;t++){ bac[t] = b_att[t*16 + sl]; wc[t] = Wsc[t*16 + sl]; }
    float b0 = bsc[0];
    for (int r=0;r<4;r++){
        int row = row0 + rbase + r;
        if (row >= n_rows) continue;
        float p = 0.f;
        #pragma unroll
        for (int t=0;t<8;t++) p += tanhf(acc[t][r] + bac[t]) * wc[t];
        p += __shfl_xor(p,1); p += __shfl_xor(p,2); p += __shfl_xor(p,4); p += __shfl_xor(p,8);
        if (sl == 0)
            scores[row] = (notsink[row] == 0) ? (p + b0) : -INFINITY;
    }
}

// ---------------- softmax-pool over sinks (no max: |score| <= ~5) ----------------

__global__ void k_sum1(const float* __restrict__ scores, float* part, int N){
    __shared__ float sh[256];
    int tid = threadIdx.x;
    float s = 0.f;
    for (int i = blockIdx.x*256 + tid; i < N; i += 256*256) s += expf(scores[i]);
    sh[tid] = s; __syncthreads();
    for (int d=128; d>0; d>>=1){ if (tid < d) sh[tid] += sh[tid+d]; __syncthreads(); }
    if (tid == 0) part[blockIdx.x] = sh[0];
}

__global__ void k_sum2(const float* __restrict__ part, float* invsum){
    __shared__ float sh[256];
    int tid = threadIdx.x;
    sh[tid] = part[tid]; __syncthreads();
    for (int d=128; d>0; d>>=1){ if (tid < d) sh[tid] += sh[tid+d]; __syncthreads(); }
    if (tid == 0) invsum[0] = 1.f / sh[0];
}

__global__ void k_emb1(const u16* __restrict__ h, const float* __restrict__ scores,
                       float* accum, int N){
    __shared__ float sh[256];
    int tid = threadIdx.x;
    int col = tid & 127, grp = tid >> 7;
    float acc = 0.f;
    for (int n = blockIdx.x*2 + grp; n < N; n += 512){
        float s = scores[n];
        if (s > -1e30f){
            float w = expf(s);
            acc += w * bf2f(h[(size_t)n*128 + col]);
        }
    }
    sh[tid] = acc; __syncthreads();
    if (tid < 128) atomicAdd(&accum[col], sh[tid] + sh[tid+128]);
}

__global__ void k_emb2(const float* __restrict__ accum, const float* __restrict__ invsum,
                       float* __restrict__ out){
    int c = threadIdx.x;
    if (c < 128) out[c] = accum[c] * invsum[0];
}

// ---------------- host launch ----------------

extern "C" void kernel_launch(void* const* d_in, const int* in_sizes, int n_in,
                              void* d_out, int out_size, void* d_ws, size_t ws_size,
                              hipStream_t stream)
{
    const float* node_feats = (const float*)d_in[0];
    const int* src     = (const int*)d_in[1];
    const int* dst     = (const int*)d_in[2];
    const float* W_in    = (const float*)d_in[3];
    const float* b_in    = (const float*)d_in[4];
    const float* Ws      = (const float*)d_in[5];
    const float* bs      = (const float*)d_in[6];
    const float* Wn      = (const float*)d_in[7];
    const float* bn      = (const float*)d_in[8];
    const float* Wg      = (const float*)d_in[9];
    const float* bg      = (const float*)d_in[10];
    const float* gamma   = (const float*)d_in[11];
    const float* beta    = (const float*)d_in[12];
    const float* W_att   = (const float*)d_in[13];
    const float* b_att   = (const float*)d_in[14];
    const float* W_score = (const float*)d_in[15];
    const float* b_score = (const float*)d_in[16];

    const int N = in_sizes[0] / 128;
    const int E = in_sizes[1];

    char* w = (char*)d_ws;
    auto alloc = [&](size_t bytes)->char* {
        char* p = w; w += (bytes + 255) & ~(size_t)255; return p;
    };
    u16* WT_in  = (u16*)alloc(128*128*2);
    u16* WT_s   = (u16*)alloc(3*128*128*2);
    u16* WT_n   = (u16*)alloc(3*128*128*2);
    u16* WT_g   = (u16*)alloc(3*128*256*2);
    u16* WT_att = (u16*)alloc(128*128*2);
    // zeroed region: cnt, notsink, emb_accum (contiguous)
    int* cnt      = (int*)alloc((size_t)N*4);
    int* notsink  = (int*)alloc((size_t)N*4);
    float* emb_accum = (float*)alloc(128*4);
    size_t zero_bytes = (size_t)((char*)(emb_accum + 128) - (char*)cnt);
    int* pos      = (int*)alloc((size_t)E*4);
    int* row_ptr  = (int*)alloc((size_t)N*4);
    int* blocksum = (int*)alloc(1024*4);
    int* csr_src  = (int*)alloc((size_t)E*4);
    float* inv_deg = (float*)alloc((size_t)N*4);
    float* haspred = (float*)alloc((size_t)N*4);
    float* scores  = (float*)alloc((size_t)N*4);
    float* part    = (float*)alloc(256*4);
    float* invsum  = (float*)alloc(256);
    u16* buf_h = (u16*)alloc((size_t)N*128*2);   // h (updated in place per layer)
    u16* buf_b = (u16*)alloc((size_t)N*128*2);   // neigh

    float* h_out   = (float*)d_out;
    float* emb_out = h_out + (size_t)N*128;

    hipMemsetAsync(cnt, 0, zero_bytes, stream);

    k_wt<<<(16384+255)/256, 256, 0, stream>>>(W_in,  WT_in,  14, 128, 16384);
    k_wt<<<(49152+255)/256, 256, 0, stream>>>(Ws,    WT_s,   14, 128, 49152);
    k_wt<<<(49152+255)/256, 256, 0, stream>>>(Wn,    WT_n,   14, 128, 49152);
    k_wt<<<(98304+255)/256, 256, 0, stream>>>(Wg,    WT_g,   15, 256, 98304);
    k_wt<<<(16384+255)/256, 256, 0, stream>>>(W_att, WT_att, 14, 128, 16384);

    k_count<<<(E+255)/256, 256, 0, stream>>>(src, dst, cnt, notsink, pos, E);

    int nb = (N + 1023) / 1024;
    k_scan1<<<nb, 256, 0, stream>>>(cnt, blocksum, N);
    k_scan2<<<1, 256, 0, stream>>>(blocksum, nb);
    k_scan3<<<nb, 256, 0, stream>>>(cnt, blocksum, row_ptr, inv_deg, haspred, N);
    k_place<<<(E+255)/256, 256, 0, stream>>>(src, dst, row_ptr, pos, csr_src, E);

    int gblk = (N + 63) / 64;
    int nblk = (N + 15) / 16;

    k_gemm_in<<<gblk, 256, 0, stream>>>(node_feats, WT_in, b_in, buf_h, N);

    for (int i=0;i<3;i++){
        k_neigh<<<nblk, 256, 0, stream>>>(buf_h, row_ptr, cnt, inv_deg, csr_src, buf_b, N);
        float* f32out = (i == 2) ? h_out : nullptr;
        k_layer<<<gblk, 256, 0, stream>>>(buf_h, buf_b,
                                          WT_s + i*16384, WT_n + i*16384, WT_g + i*32768,
                                          bs + i*128, bn + i*128, bg + i*128,
                                          gamma + i*128, beta + i*128, haspred,
                                          buf_h, f32out, N);
    }

    k_gemm_att<<<gblk, 256, 0, stream>>>(buf_h, WT_att, b_att, W_score, b_score,
                                         notsink, scores, N);
    k_sum1<<<256, 256, 0, stream>>>(scores, part, N);
    k_sum2<<<1, 256, 0, stream>>>(part, invsum);
    k_emb1<<<256, 256, 0, stream>>>(buf_h, scores, emb_accum, N);
    k_emb2<<<1, 128, 0, stream>>>(emb_accum, invsum, emb_out);

    (void)n_in; (void)out_size; (void)ws_size;
}